// Round 13
// baseline (491.624 us; speedup 1.0000x reference)
//
#include <hip/hip_runtime.h>
#include <hip/hip_bf16.h>
#include <math.h>

// Problem constants
#define DDIM   300
#define PFN    12
#define LFN    8
#define ICH    21      // PF + LF + 1
#define TPB    384     // 6 waves/block; 4 lanes per sample
#define SPB    96      // samples per block
#define SLOT_DW 99     // per-sample feature slot: 9 positions * 11 dwords
#define W1P    1980    // 20 oc * 11 icp * 9 taps  bf16-pair dwords (7920 B)
#define W2P    1200    // 30*20*2 bf16 tap-pair dwords (4800 B)
#define FW1H   2280    // 120*38/2 fc1 weights bf16-packed dwords (9120 B)
#define FW2H   5040    // 84*120/2 fc2 weights bf16-packed dwords (20160 B)

__device__ __forceinline__ float lrelu(float v) { return v > 0.0f ? v : 0.2f * v; }

__device__ __forceinline__ unsigned int pack2(float a, float b) {
    union { __hip_bfloat162 h; unsigned int u; } cv;
    cv.h.x = __float2bfloat16(a);
    cv.h.y = __float2bfloat16(b);
    return cv.u;
}
__device__ __forceinline__ float bflo(unsigned int u) {
    union { unsigned int i; float f; } c; c.i = u << 16; return c.f;
}
__device__ __forceinline__ float bfhi(unsigned int u) {
    union { unsigned int i; float f; } c; c.i = u & 0xffff0000u; return c.f;
}

// Packed bf16 dot-2 with f32 accumulate: d = a.lo*b.lo + a.hi*b.hi + c.
__device__ __forceinline__ float dot2bf(unsigned int a, unsigned int b, float c) {
    float d;
    asm("v_dot2_f32_bf16 %0, %1, %2, %3" : "=v"(d) : "v"(a), "v"(b), "v"(c));
    return d;
}

// 3x3 conv (pad=1) on a 3x3 grid: accumulate one packed ic-PAIR into 9 outputs.
__device__ __forceinline__ void conv_acc2(float o[9], const unsigned int w[9],
                                          const unsigned int fv[9]) {
#pragma unroll
    for (int t = 0; t < 9; ++t) {
        const int ky = t / 3 - 1, kx = t % 3 - 1;
        const unsigned int wv = w[t];
#pragma unroll
        for (int y = 0; y < 3; ++y) {
            const int iy = y + ky;
            if (iy < 0 || iy > 2) continue;
#pragma unroll
            for (int x = 0; x < 3; ++x) {
                const int ix = x + kx;
                if (ix < 0 || ix > 2) continue;
                o[y * 3 + x] = dot2bf(wv, fv[iy * 3 + ix], o[y * 3 + x]);
            }
        }
    }
}

// r12 post-mortem: 81,408B LDS blocks did NOT co-reside 2/CU (occ 15.8% = one
// 6-wave block) while r8's 80,896B did (occ 21%) -> usable LDS/CU is ~162KB,
// not 163.84KB. r12 ran at 1.5 waves/EU and its 206us matched the
// inverse-waves latency model (138us x 8/6). This round: identical structure
// minus the 1,356B bias[] LDS array (biases read from global; ~230 L1-hit
// loads/lane, trivial). LDS = 80,016B <= the r8-proven 2-block size ->
// 12 waves/CU = 3 waves/EU. Arithmetic bit-identical to r12.
__launch_bounds__(TPB, 3)
__global__ void disc_kernel(
    const int* __restrict__ state, const int* __restrict__ des,
    const int* __restrict__ act,
    const int* __restrict__ asp_g,   // action_state_pad (S,9)
    const int* __restrict__ pmp_g,   // policy_mask_pad  (S,9)
    const float* __restrict__ path_feature,  // (S,D,12)
    const float* __restrict__ link_feature,  // (S,8)
    const float* __restrict__ w1, const float* __restrict__ b1,   // conv1 (20,21,3,3)
    const float* __restrict__ w2, const float* __restrict__ b2,   // conv2 (30,20,2,2)
    const float* __restrict__ fw1, const float* __restrict__ fb1, // (120,38)
    const float* __restrict__ fw2, const float* __restrict__ fb2, // (84,120)
    const float* __restrict__ fw3, const float* __restrict__ fb3, // (1,84)
    float* __restrict__ out, int n)
{
    __shared__ __align__(16) unsigned int w1p[W1P];   //  7920 B bf16 ic-pairs
    __shared__ __align__(16) unsigned int w2p[W2P];   //  4800 B bf16 tap-pairs
    __shared__ __align__(16) unsigned int fw1h[FW1H]; //  9120 B bf16x2
    __shared__ __align__(16) unsigned int fw2h[FW2H]; // 20160 B bf16x2
    __shared__ unsigned int feat[SPB * SLOT_DW];      // 38016 B  => 80016 B total

    const int tid = threadIdx.x;

    // ---- Stage all weights to LDS once per block (biases stay in global).
    {
        // conv1 weights as bf16 ic-pair dwords: w1p[oc][icp][t] =
        // pack2(w1[oc][2icp][t], w1[oc][2icp+1][t]); icp==10 pairs ic20 with 0.
        for (int i = tid; i < W1P; i += TPB) {
            const int oc = i / 99, r = i % 99, icp = r / 9, t = r % 9;
            const float lo = w1[(oc * ICH + 2 * icp) * 9 + t];
            const float hi = (icp < 10) ? w1[(oc * ICH + 2 * icp + 1) * 9 + t] : 0.0f;
            w1p[i] = pack2(lo, hi);
        }
        // conv2 weights as bf16 tap-pair dwords: w2p[j][oc][h] =
        // pack2(w2[j][oc][2h], w2[j][oc][2h+1]), h in {0,1}.
        for (int i = tid; i < W2P; i += TPB) {
            const int j = i / 40, r = i % 40, oc = r / 2, h = r % 2;
            w2p[i] = pack2(w2[j * 80 + oc * 4 + 2 * h], w2[j * 80 + oc * 4 + 2 * h + 1]);
        }
        const float2* sf1 = (const float2*)fw1;
        for (int i = tid; i < FW1H; i += TPB) { const float2 v = sf1[i]; fw1h[i] = pack2(v.x, v.y); }
        const float2* sf2 = (const float2*)fw2;
        for (int i = tid; i < FW2H; i += TPB) { const float2 v = sf2[i]; fw2h[i] = pack2(v.x, v.y); }
    }
    __syncthreads();

    const int lane4  = tid & 3;       // lane within sample quad
    const int lsamp  = tid >> 2;      // sample within block
    const int sample = blockIdx.x * SPB + lsamp;
    if (sample >= n) return;

    const int s  = state[sample];
    const int d  = des[sample];
    const int ai = act[sample];

    const int* asp = asp_g + s * 9;
    const int* pmp = pmp_g + s * 9;
    unsigned int* fslot = feat + lsamp * SLOT_DW;

    // ---- Cooperative gather: lane k handles positions k, k+4, k+8.
    // NEW_INDEX packed as nibbles: p -> {7,0,1,6,8,2,5,4,3}
#pragma unroll
    for (int t = 0; t < 3; ++t) {
        const int p = lane4 + 4 * t;
        if (p < 9) {
            const int a  = (int)((0x345286107ULL >> (4 * p)) & 0xF);
            const int na = asp[a];
            const float m = (float)pmp[a];
            const float4* pf = (const float4*)(path_feature + (na * DDIM + d) * PFN);
            const float4 v0 = pf[0], v1 = pf[1], v2 = pf[2];
            const float4* lf = (const float4*)(link_feature + na * LFN);
            const float4 u0 = lf[0], u1 = lf[1];
            unsigned int* dst = fslot + p * 11;   // 22 bf16 per position (dword aligned)
            dst[0] = pack2(v0.x, v0.y); dst[1] = pack2(v0.z, v0.w);
            dst[2] = pack2(v1.x, v1.y); dst[3] = pack2(v1.z, v1.w);
            dst[4] = pack2(v2.x, v2.y); dst[5] = pack2(v2.z, v2.w);
            dst[6] = pack2(u0.x, u0.y); dst[7] = pack2(u0.z, u0.w);
            dst[8] = pack2(u1.x, u1.y); dst[9] = pack2(u1.z, u1.w);
            dst[10] = pack2(m, 0.0f);             // channel 20 = mask, high half = pad
        }
    }
    // Quad writes its own slot (same wave): drain ds_writes before reads.
    asm volatile("s_waitcnt lgkmcnt(0)" ::: "memory");

    // ---- conv1: lane k computes output channels [5k, 5k+5) via dot2 over
    // ic-pairs; 11 packed dwords cover all 21 channels (incl. mask, hi=0).
    const int oc0 = lane4 * 5;
    float o[5][9];
#pragma unroll
    for (int c = 0; c < 5; ++c) {
        const float bb = b1[oc0 + c];
#pragma unroll
        for (int q = 0; q < 9; ++q) o[c][q] = bb;
    }

#pragma unroll 1
    for (int icp = 0; icp < 11; ++icp) {
        unsigned int fwd[9];
#pragma unroll
        for (int q = 0; q < 9; ++q) fwd[q] = fslot[q * 11 + icp];
        unsigned int wt[9];
#pragma unroll
        for (int c = 0; c < 5; ++c) {
            const unsigned int* wrow = w1p + (oc0 + c) * 99 + icp * 9;
#pragma unroll
            for (int t = 0; t < 9; ++t) wt[t] = wrow[t];
            conv_acc2(o[c], wt, fwd);
        }
    }

    // ---- lrelu + 2x2 maxpool (stride 1) on local 5 channels, pack to bf16
    // pairs for conv2's dot2 path.
    unsigned int pp[5][2];
#pragma unroll
    for (int c = 0; c < 5; ++c) {
        float v[9];
#pragma unroll
        for (int q = 0; q < 9; ++q) v[q] = lrelu(o[c][q]);
        const float p0 = fmaxf(fmaxf(v[0], v[1]), fmaxf(v[3], v[4]));
        const float p1 = fmaxf(fmaxf(v[1], v[2]), fmaxf(v[4], v[5]));
        const float p2 = fmaxf(fmaxf(v[3], v[4]), fmaxf(v[6], v[7]));
        const float p3 = fmaxf(fmaxf(v[4], v[5]), fmaxf(v[7], v[8]));
        pp[c][0] = pack2(p0, p1);
        pp[c][1] = pack2(p2, p3);
    }

    // ---- conv2 (2x2 VALID) via dot2 over tap-pairs: per-lane partial over
    // its 5 oc, quad butterfly reduce. FULLY unrolled (rule #20).
    float x30[30];
#pragma unroll
    for (int j = 0; j < 30; ++j) {
        const unsigned int* wb = w2p + j * 40 + oc0 * 2;
        float acc = 0.0f;
#pragma unroll
        for (int c = 0; c < 5; ++c) {
            acc = dot2bf(wb[2 * c],     pp[c][0], acc);
            acc = dot2bf(wb[2 * c + 1], pp[c][1], acc);
        }
        acc += __shfl_xor(acc, 1, 64);
        acc += __shfl_xor(acc, 2, 64);
        x30[j] = lrelu(acc + b2[j]);
    }

    // Pack x30 once to bf16 pairs for the dot2 FC path.
    unsigned int xp[15];
#pragma unroll
    for (int m = 0; m < 15; ++m) xp[m] = pack2(x30[2 * m], x30[2 * m + 1]);

    // ---- fc1 (38->120): lane k computes rows [30k, 30k+30) via dot2.
    float h1[30];
    const int j0 = lane4 * 30;
    const int ohd   = (30 + ai) >> 1;  // one-hot dword within 19-dw row
    const int ohodd = (30 + ai) & 1;   // which bf16 half
#pragma unroll
    for (int jj = 0; jj < 30; ++jj) {
        const unsigned int* wr = fw1h + (j0 + jj) * 19;
        const unsigned int uoh = wr[ohd];
        float acc = fb1[j0 + jj] + (ohodd ? bfhi(uoh) : bflo(uoh));
#pragma unroll
        for (int m = 0; m < 15; ++m)
            acc = dot2bf(wr[m], xp[m], acc);
        h1[jj] = lrelu(acc);
    }

    // Pack h1 once to bf16 pairs.
    unsigned int hp[15];
#pragma unroll
    for (int m = 0; m < 15; ++m) hp[m] = pack2(h1[2 * m], h1[2 * m + 1]);

    // ---- fc2 (120->84) + fc3 (84->1): per-lane dot2 partial over its 30 h1,
    // butterfly reduce, fold straight into fc3 (no h2 array).
    float z = fb3[0];
#pragma unroll 2
    for (int i = 0; i < 84; ++i) {
        const unsigned int* wp = fw2h + i * 60 + lane4 * 15;
        float a = 0.0f;
#pragma unroll
        for (int m = 0; m < 15; ++m)
            a = dot2bf(wp[m], hp[m], a);
        a += __shfl_xor(a, 1, 64);
        a += __shfl_xor(a, 2, 64);
        z = fmaf(fw3[i], lrelu(a + fb2[i]), z);
    }

    if (lane4 == 0)
        out[sample] = 1.0f / (1.0f + __expf(-z));
}

extern "C" void kernel_launch(void* const* d_in, const int* in_sizes, int n_in,
                              void* d_out, int out_size, void* d_ws, size_t ws_size,
                              hipStream_t stream) {
    const int*   state = (const int*)d_in[0];
    const int*   des   = (const int*)d_in[1];
    const int*   act   = (const int*)d_in[2];
    const int*   asp   = (const int*)d_in[3];
    const int*   pmp   = (const int*)d_in[4];
    const float* pathf = (const float*)d_in[5];
    const float* linkf = (const float*)d_in[6];
    const float* w1    = (const float*)d_in[7];
    const float* b1    = (const float*)d_in[8];
    const float* w2    = (const float*)d_in[9];
    const float* b2    = (const float*)d_in[10];
    const float* fw1   = (const float*)d_in[11];
    const float* fb1   = (const float*)d_in[12];
    const float* fw2   = (const float*)d_in[13];
    const float* fb2   = (const float*)d_in[14];
    const float* fw3   = (const float*)d_in[15];
    const float* fb3   = (const float*)d_in[16];

    const int n = in_sizes[0];
    dim3 grid((n + SPB - 1) / SPB), block(TPB);
    hipLaunchKernelGGL(disc_kernel, grid, block, 0, stream,
                       state, des, act, asp, pmp, pathf, linkf,
                       w1, b1, w2, b2, fw1, fb1, fw2, fb2, fw3, fb3,
                       (float*)d_out, n);
}

// Round 14
// 485.578 us; speedup vs baseline: 1.0125x; 1.0125x over previous
//
#include <hip/hip_runtime.h>
#include <hip/hip_bf16.h>
#include <math.h>

// Problem constants
#define DDIM   300
#define PFN    12
#define LFN    8
#define ICH    21      // PF + LF + 1
#define TPB    512     // 8 waves/block; 4 lanes per sample
#define SPB    128     // samples per block -> grid = 65536/128 = 512 = 2/CU EXACTLY
#define SLOT_DW 99     // per-sample feature slot: 9 positions * 11 dwords
#define W1P    1980    // 20 oc * 11 icp * 9 taps  bf16-pair dwords (7920 B)
#define FW2H   5040    // 84*120/2 fc2 weights bf16-packed dwords (20160 B)

__device__ __forceinline__ float lrelu(float v) { return v > 0.0f ? v : 0.2f * v; }

__device__ __forceinline__ unsigned int pack2(float a, float b) {
    union { __hip_bfloat162 h; unsigned int u; } cv;
    cv.h.x = __float2bfloat16(a);
    cv.h.y = __float2bfloat16(b);
    return cv.u;
}
__device__ __forceinline__ float bflo(unsigned int u) {
    union { unsigned int i; float f; } c; c.i = u << 16; return c.f;
}
__device__ __forceinline__ float bfhi(unsigned int u) {
    union { unsigned int i; float f; } c; c.i = u & 0xffff0000u; return c.f;
}

// Packed bf16 dot-2 with f32 accumulate: d = a.lo*b.lo + a.hi*b.hi + c.
__device__ __forceinline__ float dot2bf(unsigned int a, unsigned int b, float c) {
    float d;
    asm("v_dot2_f32_bf16 %0, %1, %2, %3" : "=v"(d) : "v"(a), "v"(b), "v"(c));
    return d;
}

// 3x3 conv (pad=1) on a 3x3 grid: accumulate one packed ic-PAIR into 9 outputs.
// Weight taps read inline from LDS and consumed immediately (live ~1 reg, not 9).
__device__ __forceinline__ void conv_acc2(float o[9], const unsigned int* __restrict__ w,
                                          const unsigned int fv[9]) {
#pragma unroll
    for (int t = 0; t < 9; ++t) {
        const int ky = t / 3 - 1, kx = t % 3 - 1;
        const unsigned int wv = w[t];
#pragma unroll
        for (int y = 0; y < 3; ++y) {
            const int iy = y + ky;
            if (iy < 0 || iy > 2) continue;
#pragma unroll
            for (int x = 0; x < 3; ++x) {
                const int ix = x + kx;
                if (ix < 0 || ix > 2) continue;
                o[y * 3 + x] = dot2bf(wv, fv[iy * 3 + ix], o[y * 3 + x]);
            }
        }
    }
}

// r12/r13 makespan lesson: with 256 samples/CU, any plan whose blocks/CU
// isn't a clean multiple of the concurrency has a dispatch tail that eats
// the occupancy gain (r13's 683 blocks @ 2.67/CU == r9's makespan exactly).
// The only winning shape: ONE round with all waves resident. This kernel:
// 512 blocks (2/CU, both co-resident) x 8 waves = 16 waves/CU = 4 waves/EU.
// LDS = w1p + fw2h + feat = 78,768B <= 80,896 (r8-proven 2-block size).
// launch_bounds(512,4) -> 64-VGPR budget (session model: 256/W): conv1 peak
// live ~= o[45]+fwd[9]+misc ~= 60. conv2/fc1 weights + biases from global
// (w2 9.6K, fw1 18K: L1-resident; addresses wave-uniform per lane4 -> 4
// cache lines/instr). conv2 back to f32 fmaf (absmax improves vs r12/r13).
__launch_bounds__(TPB, 4)
__global__ void disc_kernel(
    const int* __restrict__ state, const int* __restrict__ des,
    const int* __restrict__ act,
    const int* __restrict__ asp_g,   // action_state_pad (S,9)
    const int* __restrict__ pmp_g,   // policy_mask_pad  (S,9)
    const float* __restrict__ path_feature,  // (S,D,12)
    const float* __restrict__ link_feature,  // (S,8)
    const float* __restrict__ w1, const float* __restrict__ b1,   // conv1 (20,21,3,3)
    const float* __restrict__ w2, const float* __restrict__ b2,   // conv2 (30,20,2,2)
    const float* __restrict__ fw1, const float* __restrict__ fb1, // (120,38)
    const float* __restrict__ fw2, const float* __restrict__ fb2, // (84,120)
    const float* __restrict__ fw3, const float* __restrict__ fb3, // (1,84)
    float* __restrict__ out, int n)
{
    __shared__ __align__(16) unsigned int w1p[W1P];   //  7920 B bf16 ic-pairs
    __shared__ __align__(16) unsigned int fw2h[FW2H]; // 20160 B bf16x2
    __shared__ unsigned int feat[SPB * SLOT_DW];      // 50688 B  => 78768 B total

    const int tid = threadIdx.x;

    // ---- Stage conv1 + fc2 weights to LDS once per block.
    {
        // conv1 weights as bf16 ic-pair dwords: w1p[oc][icp][t] =
        // pack2(w1[oc][2icp][t], w1[oc][2icp+1][t]); icp==10 pairs ic20 with 0.
        for (int i = tid; i < W1P; i += TPB) {
            const int oc = i / 99, r = i % 99, icp = r / 9, t = r % 9;
            const float lo = w1[(oc * ICH + 2 * icp) * 9 + t];
            const float hi = (icp < 10) ? w1[(oc * ICH + 2 * icp + 1) * 9 + t] : 0.0f;
            w1p[i] = pack2(lo, hi);
        }
        const float2* sf2 = (const float2*)fw2;
        for (int i = tid; i < FW2H; i += TPB) { const float2 v = sf2[i]; fw2h[i] = pack2(v.x, v.y); }
    }
    __syncthreads();

    const int lane4  = tid & 3;       // lane within sample quad
    const int lsamp  = tid >> 2;      // sample within block
    const int sample = blockIdx.x * SPB + lsamp;
    if (sample >= n) return;

    const int s  = state[sample];
    const int d  = des[sample];
    const int ai = act[sample];

    const int* asp = asp_g + s * 9;
    const int* pmp = pmp_g + s * 9;
    unsigned int* fslot = feat + lsamp * SLOT_DW;

    // ---- Cooperative gather: lane k handles positions k, k+4, k+8.
    // NEW_INDEX packed as nibbles: p -> {7,0,1,6,8,2,5,4,3}
#pragma unroll
    for (int t = 0; t < 3; ++t) {
        const int p = lane4 + 4 * t;
        if (p < 9) {
            const int a  = (int)((0x345286107ULL >> (4 * p)) & 0xF);
            const int na = asp[a];
            const float m = (float)pmp[a];
            const float4* pf = (const float4*)(path_feature + (na * DDIM + d) * PFN);
            const float4 v0 = pf[0], v1 = pf[1], v2 = pf[2];
            const float4* lf = (const float4*)(link_feature + na * LFN);
            const float4 u0 = lf[0], u1 = lf[1];
            unsigned int* dst = fslot + p * 11;   // 22 bf16 per position (dword aligned)
            dst[0] = pack2(v0.x, v0.y); dst[1] = pack2(v0.z, v0.w);
            dst[2] = pack2(v1.x, v1.y); dst[3] = pack2(v1.z, v1.w);
            dst[4] = pack2(v2.x, v2.y); dst[5] = pack2(v2.z, v2.w);
            dst[6] = pack2(u0.x, u0.y); dst[7] = pack2(u0.z, u0.w);
            dst[8] = pack2(u1.x, u1.y); dst[9] = pack2(u1.z, u1.w);
            dst[10] = pack2(m, 0.0f);             // channel 20 = mask, high half = pad
        }
    }
    // Quad writes its own slot (same wave; 4-lane groups never cross a wave
    // boundary): drain our ds_writes before cross-lane reads.
    asm volatile("s_waitcnt lgkmcnt(0)" ::: "memory");

    // ---- conv1: lane k computes output channels [5k, 5k+5) via dot2 over
    // ic-pairs; 11 packed dwords cover all 21 channels (incl. mask, hi=0).
    const int oc0 = lane4 * 5;
    float o[5][9];
#pragma unroll
    for (int c = 0; c < 5; ++c) {
        const float bb = b1[oc0 + c];
#pragma unroll
        for (int q = 0; q < 9; ++q) o[c][q] = bb;
    }

#pragma unroll 1
    for (int icp = 0; icp < 11; ++icp) {
        unsigned int fwd[9];
#pragma unroll
        for (int q = 0; q < 9; ++q) fwd[q] = fslot[q * 11 + icp];
#pragma unroll
        for (int c = 0; c < 5; ++c)
            conv_acc2(o[c], w1p + (oc0 + c) * 99 + icp * 9, fwd);
    }

    // ---- lrelu + 2x2 maxpool (stride 1) on local 5 channels
    float pooled[5][4];
#pragma unroll
    for (int c = 0; c < 5; ++c) {
        float v[9];
#pragma unroll
        for (int q = 0; q < 9; ++q) v[q] = lrelu(o[c][q]);
        pooled[c][0] = fmaxf(fmaxf(v[0], v[1]), fmaxf(v[3], v[4]));
        pooled[c][1] = fmaxf(fmaxf(v[1], v[2]), fmaxf(v[4], v[5]));
        pooled[c][2] = fmaxf(fmaxf(v[3], v[4]), fmaxf(v[6], v[7]));
        pooled[c][3] = fmaxf(fmaxf(v[4], v[5]), fmaxf(v[7], v[8]));
    }

    // ---- conv2 (2x2 VALID): f32 weights from GLOBAL (9.6K, L1-resident;
    // 4 distinct addrs/instr), per-lane partial over its 5 oc, quad butterfly.
    // x30 consumed pair-wise into packed xp (x30 never a live array).
    unsigned int xp[15];
#pragma unroll
    for (int jp = 0; jp < 15; ++jp) {
        float xa[2];
#pragma unroll
        for (int h = 0; h < 2; ++h) {
            const int j = 2 * jp + h;
            const float4* wr = (const float4*)(w2 + j * 80 + oc0 * 4);  // 16B aligned
            float acc = 0.0f;
#pragma unroll
            for (int c = 0; c < 5; ++c) {
                const float4 wv = wr[c];
                acc = fmaf(wv.x, pooled[c][0], acc);
                acc = fmaf(wv.y, pooled[c][1], acc);
                acc = fmaf(wv.z, pooled[c][2], acc);
                acc = fmaf(wv.w, pooled[c][3], acc);
            }
            acc += __shfl_xor(acc, 1, 64);
            acc += __shfl_xor(acc, 2, 64);
            xa[h] = lrelu(acc + b2[j]);
        }
        xp[jp] = pack2(xa[0], xa[1]);
    }

    // ---- fc1 (38->120): lane k computes rows [30k, 30k+30); weights from
    // GLOBAL f32 (18K, L1-resident), packed on the fly -> dot2 with xp.
    // h1 rows packed pair-wise straight into hp (no live h1 array).
    unsigned int hp[15];
    const int j0 = lane4 * 30;
#pragma unroll
    for (int jp = 0; jp < 15; ++jp) {
        float ha[2];
#pragma unroll
        for (int h = 0; h < 2; ++h) {
            const int jj = 2 * jp + h;
            const float* wr = fw1 + (j0 + jj) * 38;
            float acc = fb1[j0 + jj] + wr[30 + ai];   // one-hot(act) contribution
            const float2* wp = (const float2*)wr;     // 8B aligned (38*4 = 152)
#pragma unroll
            for (int m = 0; m < 15; ++m) {
                const float2 wv = wp[m];
                acc = dot2bf(pack2(wv.x, wv.y), xp[m], acc);
            }
            ha[h] = lrelu(acc);
        }
        hp[jp] = pack2(ha[0], ha[1]);
    }

    // ---- fc2 (120->84) + fc3 (84->1): per-lane dot2 partial over its 30 h1
    // (bf16 weights from LDS, r9-proven 60-dw layout), butterfly reduce,
    // fold straight into fc3 (no h2 array).
    float z = fb3[0];
#pragma unroll 2
    for (int i = 0; i < 84; ++i) {
        const unsigned int* wp = fw2h + i * 60 + lane4 * 15;
        float a = 0.0f;
#pragma unroll
        for (int m = 0; m < 15; ++m)
            a = dot2bf(wp[m], hp[m], a);
        a += __shfl_xor(a, 1, 64);
        a += __shfl_xor(a, 2, 64);
        z = fmaf(fw3[i], lrelu(a + fb2[i]), z);
    }

    if (lane4 == 0)
        out[sample] = 1.0f / (1.0f + __expf(-z));
}

extern "C" void kernel_launch(void* const* d_in, const int* in_sizes, int n_in,
                              void* d_out, int out_size, void* d_ws, size_t ws_size,
                              hipStream_t stream) {
    const int*   state = (const int*)d_in[0];
    const int*   des   = (const int*)d_in[1];
    const int*   act   = (const int*)d_in[2];
    const int*   asp   = (const int*)d_in[3];
    const int*   pmp   = (const int*)d_in[4];
    const float* pathf = (const float*)d_in[5];
    const float* linkf = (const float*)d_in[6];
    const float* w1    = (const float*)d_in[7];
    const float* b1    = (const float*)d_in[8];
    const float* w2    = (const float*)d_in[9];
    const float* b2    = (const float*)d_in[10];
    const float* fw1   = (const float*)d_in[11];
    const float* fb1   = (const float*)d_in[12];
    const float* fw2   = (const float*)d_in[13];
    const float* fb2   = (const float*)d_in[14];
    const float* fw3   = (const float*)d_in[15];
    const float* fb3   = (const float*)d_in[16];

    const int n = in_sizes[0];
    dim3 grid((n + SPB - 1) / SPB), block(TPB);
    hipLaunchKernelGGL(disc_kernel, grid, block, 0, stream,
                       state, des, act, asp, pmp, pathf, linkf,
                       w1, b1, w2, b2, fw1, fb1, fw2, fb2, fw3, fb3,
                       (float*)d_out, n);
}

// Round 15
// 440.456 us; speedup vs baseline: 1.1162x; 1.1024x over previous
//
#include <hip/hip_runtime.h>
#include <hip/hip_bf16.h>
#include <math.h>

// Problem constants
#define DDIM   300
#define PFN    12
#define LFN    8
#define ICH    21      // PF + LF + 1
#define TPB    1024    // 16 waves/block; 4 lanes per sample
#define SPB    256     // samples per block -> grid = 65536/256 = 256 = 1 block/CU EXACTLY
#define SLOT_DW 99     // per-sample feature slot: 9 positions * 11 dwords
#define W1P    1980    // 20 oc * 11 icp * 9 taps  bf16-pair dwords (7920 B)
#define W2N    2400    // 30*20*4  conv2 weights fp32 (9600 B)
#define FW1H   2280    // 120*38/2 fc1 weights bf16-packed dwords (9120 B)
#define FW2H   5040    // 84*120/2 fc2 weights bf16-packed dwords (20160 B)
#define BIASN  339     // b1(20)+b2(30)+fb1(120)+fb2(84)+fw3(84)+fb3(1)
// bias[] layout offsets:
#define OB1    0
#define OB2    20
#define OFB1   50
#define OFB2   170
#define OFW3   254
#define OFB3   338

__device__ __forceinline__ float lrelu(float v) { return v > 0.0f ? v : 0.2f * v; }

__device__ __forceinline__ unsigned int pack2(float a, float b) {
    union { __hip_bfloat162 h; unsigned int u; } cv;
    cv.h.x = __float2bfloat16(a);
    cv.h.y = __float2bfloat16(b);
    return cv.u;
}
__device__ __forceinline__ float bflo(unsigned int u) {
    union { unsigned int i; float f; } c; c.i = u << 16; return c.f;
}
__device__ __forceinline__ float bfhi(unsigned int u) {
    union { unsigned int i; float f; } c; c.i = u & 0xffff0000u; return c.f;
}

// Packed bf16 dot-2 with f32 accumulate: d = a.lo*b.lo + a.hi*b.hi + c.
__device__ __forceinline__ float dot2bf(unsigned int a, unsigned int b, float c) {
    float d;
    asm("v_dot2_f32_bf16 %0, %1, %2, %3" : "=v"(d) : "v"(a), "v"(b), "v"(c));
    return d;
}

// 3x3 conv (pad=1) on a 3x3 grid: accumulate one packed ic-PAIR into 9 outputs.
__device__ __forceinline__ void conv_acc2(float o[9], const unsigned int w[9],
                                          const unsigned int fv[9]) {
#pragma unroll
    for (int t = 0; t < 9; ++t) {
        const int ky = t / 3 - 1, kx = t % 3 - 1;
        const unsigned int wv = w[t];
#pragma unroll
        for (int y = 0; y < 3; ++y) {
            const int iy = y + ky;
            if (iy < 0 || iy > 2) continue;
#pragma unroll
            for (int x = 0; x < 3; ++x) {
                const int ix = x + kx;
                if (ix < 0 || ix > 2) continue;
                o[y * 3 + x] = dot2bf(wv, fv[iy * 3 + ix], o[y * 3 + x]);
            }
        }
    }
}

// Rounds 10-14 negative result: every deviation from r9's all-weights-in-LDS
// structure lost (VMEM weight streams, spills at <128 VGPR, dispatch tails).
// This round keeps r9's body BYTE-IDENTICAL and changes only the residency
// shape: TPB=1024 / SPB=256 -> 256 blocks = exactly 1/CU, zero tail, one
// round. With ONE block per CU the LDS budget is the full ~162KB, so r9's
// complete layout (all weights + bias + feat@256) = 149,532B fits. A 16-wave
// block is all-or-nothing resident -> 4 waves/SIMD (allowed at exactly 128
// VGPR, the tier boundary). launch_bounds(1024,2) keeps the proven 128-VGPR
// budget (session model: budget = 256/W). Weight staging amortizes 4x better.
__launch_bounds__(TPB, 2)
__global__ void disc_kernel(
    const int* __restrict__ state, const int* __restrict__ des,
    const int* __restrict__ act,
    const int* __restrict__ asp_g,   // action_state_pad (S,9)
    const int* __restrict__ pmp_g,   // policy_mask_pad  (S,9)
    const float* __restrict__ path_feature,  // (S,D,12)
    const float* __restrict__ link_feature,  // (S,8)
    const float* __restrict__ w1, const float* __restrict__ b1,   // conv1 (20,21,3,3)
    const float* __restrict__ w2, const float* __restrict__ b2,   // conv2 (30,20,2,2)
    const float* __restrict__ fw1, const float* __restrict__ fb1, // (120,38)
    const float* __restrict__ fw2, const float* __restrict__ fb2, // (84,120)
    const float* __restrict__ fw3, const float* __restrict__ fb3, // (1,84)
    float* __restrict__ out, int n)
{
    __shared__ __align__(16) unsigned int w1p[W1P];   //   7920 B bf16 ic-pairs
    __shared__ __align__(16) float w2s[W2N];          //   9600 B fp32
    __shared__ __align__(16) unsigned int fw1h[FW1H]; //   9120 B bf16x2
    __shared__ __align__(16) unsigned int fw2h[FW2H]; //  20160 B bf16x2
    __shared__ float bias[BIASN];                     //   1356 B fp32
    __shared__ unsigned int feat[SPB * SLOT_DW];      // 101376 B  => 149532 B total

    const int tid = threadIdx.x;

    // ---- Stage all weights/biases to LDS once per block (= once per CU).
    {
        // conv1 weights as bf16 ic-pair dwords: w1p[oc][icp][t] =
        // pack2(w1[oc][2icp][t], w1[oc][2icp+1][t]); icp==10 pairs ic20 with 0.
        for (int i = tid; i < W1P; i += TPB) {
            const int oc = i / 99, r = i % 99, icp = r / 9, t = r % 9;
            const float lo = w1[(oc * ICH + 2 * icp) * 9 + t];
            const float hi = (icp < 10) ? w1[(oc * ICH + 2 * icp + 1) * 9 + t] : 0.0f;
            w1p[i] = pack2(lo, hi);
        }
        const float4* s2 = (const float4*)w2;  float4* d2 = (float4*)w2s;
        for (int i = tid; i < W2N / 4; i += TPB) d2[i] = s2[i];
        const float2* sf1 = (const float2*)fw1;
        for (int i = tid; i < FW1H; i += TPB) { const float2 v = sf1[i]; fw1h[i] = pack2(v.x, v.y); }
        const float2* sf2 = (const float2*)fw2;
        for (int i = tid; i < FW2H; i += TPB) { const float2 v = sf2[i]; fw2h[i] = pack2(v.x, v.y); }
        for (int i = tid; i < BIASN; i += TPB) {
            float v;
            if      (i < OB2)  v = b1[i];
            else if (i < OFB1) v = b2[i - OB2];
            else if (i < OFB2) v = fb1[i - OFB1];
            else if (i < OFW3) v = fb2[i - OFB2];
            else if (i < OFB3) v = fw3[i - OFW3];
            else               v = fb3[0];
            bias[i] = v;
        }
    }
    __syncthreads();

    const int lane4  = tid & 3;       // lane within sample quad
    const int lsamp  = tid >> 2;      // sample within block
    const int sample = blockIdx.x * SPB + lsamp;
    if (sample >= n) return;

    const int s  = state[sample];
    const int d  = des[sample];
    const int ai = act[sample];

    const int* asp = asp_g + s * 9;
    const int* pmp = pmp_g + s * 9;
    unsigned int* fslot = feat + lsamp * SLOT_DW;

    // ---- Cooperative gather: lane k handles positions k, k+4, k+8.
    // NEW_INDEX packed as nibbles: p -> {7,0,1,6,8,2,5,4,3}
#pragma unroll
    for (int t = 0; t < 3; ++t) {
        const int p = lane4 + 4 * t;
        if (p < 9) {
            const int a  = (int)((0x345286107ULL >> (4 * p)) & 0xF);
            const int na = asp[a];
            const float m = (float)pmp[a];
            const float4* pf = (const float4*)(path_feature + (na * DDIM + d) * PFN);
            const float4 v0 = pf[0], v1 = pf[1], v2 = pf[2];
            const float4* lf = (const float4*)(link_feature + na * LFN);
            const float4 u0 = lf[0], u1 = lf[1];
            unsigned int* dst = fslot + p * 11;   // 22 bf16 per position (dword aligned)
            dst[0] = pack2(v0.x, v0.y); dst[1] = pack2(v0.z, v0.w);
            dst[2] = pack2(v1.x, v1.y); dst[3] = pack2(v1.z, v1.w);
            dst[4] = pack2(v2.x, v2.y); dst[5] = pack2(v2.z, v2.w);
            dst[6] = pack2(u0.x, u0.y); dst[7] = pack2(u0.z, u0.w);
            dst[8] = pack2(u1.x, u1.y); dst[9] = pack2(u1.z, u1.w);
            dst[10] = pack2(m, 0.0f);             // channel 20 = mask, high half = pad
        }
    }
    // Quad writes its own slot; quads never cross a wave boundary, so
    // draining our wave's ds_writes orders the cross-lane reads.
    asm volatile("s_waitcnt lgkmcnt(0)" ::: "memory");

    // ---- conv1: lane k computes output channels [5k, 5k+5) via dot2 over
    // ic-pairs; 11 packed dwords cover all 21 channels (incl. mask, hi=0).
    const int oc0 = lane4 * 5;
    float o[5][9];
#pragma unroll
    for (int c = 0; c < 5; ++c) {
        const float bb = bias[OB1 + oc0 + c];
#pragma unroll
        for (int q = 0; q < 9; ++q) o[c][q] = bb;
    }

#pragma unroll 1
    for (int icp = 0; icp < 11; ++icp) {
        unsigned int fwd[9];
#pragma unroll
        for (int q = 0; q < 9; ++q) fwd[q] = fslot[q * 11 + icp];
        unsigned int wt[9];
#pragma unroll
        for (int c = 0; c < 5; ++c) {
            const unsigned int* wrow = w1p + (oc0 + c) * 99 + icp * 9;
#pragma unroll
            for (int t = 0; t < 9; ++t) wt[t] = wrow[t];
            conv_acc2(o[c], wt, fwd);
        }
    }

    // ---- lrelu + 2x2 maxpool (stride 1) on local 5 channels
    float pooled[5][4];
#pragma unroll
    for (int c = 0; c < 5; ++c) {
        float v[9];
#pragma unroll
        for (int q = 0; q < 9; ++q) v[q] = lrelu(o[c][q]);
        pooled[c][0] = fmaxf(fmaxf(v[0], v[1]), fmaxf(v[3], v[4]));
        pooled[c][1] = fmaxf(fmaxf(v[1], v[2]), fmaxf(v[4], v[5]));
        pooled[c][2] = fmaxf(fmaxf(v[3], v[4]), fmaxf(v[6], v[7]));
        pooled[c][3] = fmaxf(fmaxf(v[4], v[5]), fmaxf(v[7], v[8]));
    }

    // ---- conv2 (2x2 VALID): per-lane partial over its 5 oc (f32 weights from
    // LDS; quad starts {0,20,8,28} banks -> conflict-free), butterfly reduce.
    float x30[30];
#pragma unroll
    for (int j = 0; j < 30; ++j) {
        const float4* wr = (const float4*)(w2s + j * 80 + oc0 * 4);  // 16B aligned
        float acc = 0.0f;
#pragma unroll
        for (int c = 0; c < 5; ++c) {
            const float4 wv = wr[c];
            acc = fmaf(wv.x, pooled[c][0], acc);
            acc = fmaf(wv.y, pooled[c][1], acc);
            acc = fmaf(wv.z, pooled[c][2], acc);
            acc = fmaf(wv.w, pooled[c][3], acc);
        }
        acc += __shfl_xor(acc, 1, 64);
        acc += __shfl_xor(acc, 2, 64);
        x30[j] = lrelu(acc + bias[OB2 + j]);
    }

    // Pack x30 once to bf16 pairs for the dot2 FC path.
    unsigned int xp[15];
#pragma unroll
    for (int m = 0; m < 15; ++m) xp[m] = pack2(x30[2 * m], x30[2 * m + 1]);

    // ---- fc1 (38->120): lane k computes rows [30k, 30k+30) via dot2.
    float h1[30];
    const int j0 = lane4 * 30;
    const int ohd   = (30 + ai) >> 1;  // one-hot dword within 19-dw row
    const int ohodd = (30 + ai) & 1;   // which bf16 half
#pragma unroll
    for (int jj = 0; jj < 30; ++jj) {
        const unsigned int* wr = fw1h + (j0 + jj) * 19;
        const unsigned int uoh = wr[ohd];
        float acc = bias[OFB1 + j0 + jj] + (ohodd ? bfhi(uoh) : bflo(uoh));
#pragma unroll
        for (int m = 0; m < 15; ++m)
            acc = dot2bf(wr[m], xp[m], acc);
        h1[jj] = lrelu(acc);
    }

    // Pack h1 once to bf16 pairs.
    unsigned int hp[15];
#pragma unroll
    for (int m = 0; m < 15; ++m) hp[m] = pack2(h1[2 * m], h1[2 * m + 1]);

    // ---- fc2 (120->84) + fc3 (84->1): per-lane dot2 partial over its 30 h1,
    // butterfly reduce, fold straight into fc3 (no h2 array).
    float z = bias[OFB3];
#pragma unroll 2
    for (int i = 0; i < 84; ++i) {
        const unsigned int* wp = fw2h + i * 60 + lane4 * 15;
        float a = 0.0f;
#pragma unroll
        for (int m = 0; m < 15; ++m)
            a = dot2bf(wp[m], hp[m], a);
        a += __shfl_xor(a, 1, 64);
        a += __shfl_xor(a, 2, 64);
        z = fmaf(bias[OFW3 + i], lrelu(a + bias[OFB2 + i]), z);
    }

    if (lane4 == 0)
        out[sample] = 1.0f / (1.0f + __expf(-z));
}

extern "C" void kernel_launch(void* const* d_in, const int* in_sizes, int n_in,
                              void* d_out, int out_size, void* d_ws, size_t ws_size,
                              hipStream_t stream) {
    const int*   state = (const int*)d_in[0];
    const int*   des   = (const int*)d_in[1];
    const int*   act   = (const int*)d_in[2];
    const int*   asp   = (const int*)d_in[3];
    const int*   pmp   = (const int*)d_in[4];
    const float* pathf = (const float*)d_in[5];
    const float* linkf = (const float*)d_in[6];
    const float* w1    = (const float*)d_in[7];
    const float* b1    = (const float*)d_in[8];
    const float* w2    = (const float*)d_in[9];
    const float* b2    = (const float*)d_in[10];
    const float* fw1   = (const float*)d_in[11];
    const float* fb1   = (const float*)d_in[12];
    const float* fw2   = (const float*)d_in[13];
    const float* fb2   = (const float*)d_in[14];
    const float* fw3   = (const float*)d_in[15];
    const float* fb3   = (const float*)d_in[16];

    const int n = in_sizes[0];
    dim3 grid((n + SPB - 1) / SPB), block(TPB);
    hipLaunchKernelGGL(disc_kernel, grid, block, 0, stream,
                       state, des, act, asp, pmp, pathf, linkf,
                       w1, b1, w2, b2, fw1, fb1, fw2, fb2, fw3, fb3,
                       (float*)d_out, n);
}

// Round 16
// 430.559 us; speedup vs baseline: 1.1418x; 1.0230x over previous
//
#include <hip/hip_runtime.h>
#include <hip/hip_bf16.h>
#include <math.h>

// Problem constants
#define DDIM   300
#define PFN    12
#define LFN    8
#define ICH    21      // PF + LF + 1
#define TPB    1024    // 16 waves/block; 4 lanes per sample
#define SPB    256     // samples per block -> grid = 256 = 1 block/CU EXACTLY
#define SLOT_DW 99     // per-sample feature slot: 9 positions * 11 dwords
#define W1P    1980    // 20 oc * 11 icp * 9 taps  bf16-pair dwords (7920 B)
#define W2N    2400    // 30*20*4  conv2 weights fp32 (9600 B)
#define FW1H   2280    // 120*38/2 fc1 weights bf16-packed dwords (9120 B)
#define FW2P   6720    // 84 rows * 4 chunks * 20 dw (15 data + 5 pad) (26880 B)
#define BIASN  339     // b1(20)+b2(30)+fb1(120)+fb2(84)+fw3(84)+fb3(1)
// bias[] layout offsets:
#define OB1    0
#define OB2    20
#define OFB1   50
#define OFB2   170
#define OFW3   254
#define OFB3   338

__device__ __forceinline__ float lrelu(float v) { return v > 0.0f ? v : 0.2f * v; }

__device__ __forceinline__ unsigned int pack2(float a, float b) {
    union { __hip_bfloat162 h; unsigned int u; } cv;
    cv.h.x = __float2bfloat16(a);
    cv.h.y = __float2bfloat16(b);
    return cv.u;
}
__device__ __forceinline__ float bflo(unsigned int u) {
    union { unsigned int i; float f; } c; c.i = u << 16; return c.f;
}
__device__ __forceinline__ float bfhi(unsigned int u) {
    union { unsigned int i; float f; } c; c.i = u & 0xffff0000u; return c.f;
}

// Packed bf16 dot-2 with f32 accumulate: d = a.lo*b.lo + a.hi*b.hi + c.
__device__ __forceinline__ float dot2bf(unsigned int a, unsigned int b, float c) {
    float d;
    asm("v_dot2_f32_bf16 %0, %1, %2, %3" : "=v"(d) : "v"(a), "v"(b), "v"(c));
    return d;
}

// 3x3 conv (pad=1) on a 3x3 grid: accumulate one packed ic-PAIR into 9 outputs.
__device__ __forceinline__ void conv_acc2(float o[9], const unsigned int w[9],
                                          const unsigned int fv[9]) {
#pragma unroll
    for (int t = 0; t < 9; ++t) {
        const int ky = t / 3 - 1, kx = t % 3 - 1;
        const unsigned int wv = w[t];
#pragma unroll
        for (int y = 0; y < 3; ++y) {
            const int iy = y + ky;
            if (iy < 0 || iy > 2) continue;
#pragma unroll
            for (int x = 0; x < 3; ++x) {
                const int ix = x + kx;
                if (ix < 0 || ix > 2) continue;
                o[y * 3 + x] = dot2bf(wv, fv[iy * 3 + ix], o[y * 3 + x]);
            }
        }
    }
}

// r15 (1 block/CU, 16 waves, all-LDS weights) = best known, kernel ~118us.
// At 4 waves/SIMD the DS-issue pipe is ~1/3 loaded (16 waves x ~1680 DS
// instrs) — r11's conflict-free fc2 b128 layout was NULL at 2 waves/EU
// (latency-bound regime: saved slots were idle) but should convert now.
// This round: r15 + r11's 20-dw-staggered fc2 chunks (quad bank starts
// {0,20,8,28}, all 4 sequential b128s disjoint -> fc2 DS 1260 -> 336/wave)
// + dual-accumulator dot chains in fc2 (halved dep latency). LDS 156,252B,
// still 1 block/CU. Everything else byte-identical to r15.
__launch_bounds__(TPB, 2)
__global__ void disc_kernel(
    const int* __restrict__ state, const int* __restrict__ des,
    const int* __restrict__ act,
    const int* __restrict__ asp_g,   // action_state_pad (S,9)
    const int* __restrict__ pmp_g,   // policy_mask_pad  (S,9)
    const float* __restrict__ path_feature,  // (S,D,12)
    const float* __restrict__ link_feature,  // (S,8)
    const float* __restrict__ w1, const float* __restrict__ b1,   // conv1 (20,21,3,3)
    const float* __restrict__ w2, const float* __restrict__ b2,   // conv2 (30,20,2,2)
    const float* __restrict__ fw1, const float* __restrict__ fb1, // (120,38)
    const float* __restrict__ fw2, const float* __restrict__ fb2, // (84,120)
    const float* __restrict__ fw3, const float* __restrict__ fb3, // (1,84)
    float* __restrict__ out, int n)
{
    __shared__ __align__(16) unsigned int w1p[W1P];   //   7920 B bf16 ic-pairs
    __shared__ __align__(16) float w2s[W2N];          //   9600 B fp32
    __shared__ __align__(16) unsigned int fw1h[FW1H]; //   9120 B bf16x2
    __shared__ __align__(16) unsigned int fw2h[FW2P]; //  26880 B bf16x2, 20-dw chunks
    __shared__ float bias[BIASN];                     //   1356 B fp32
    __shared__ unsigned int feat[SPB * SLOT_DW];      // 101376 B  => 156252 B total

    const int tid = threadIdx.x;

    // ---- Stage all weights/biases to LDS once per block (= once per CU).
    {
        // conv1 weights as bf16 ic-pair dwords: w1p[oc][icp][t] =
        // pack2(w1[oc][2icp][t], w1[oc][2icp+1][t]); icp==10 pairs ic20 with 0.
        for (int i = tid; i < W1P; i += TPB) {
            const int oc = i / 99, r = i % 99, icp = r / 9, t = r % 9;
            const float lo = w1[(oc * ICH + 2 * icp) * 9 + t];
            const float hi = (icp < 10) ? w1[(oc * ICH + 2 * icp + 1) * 9 + t] : 0.0f;
            w1p[i] = pack2(lo, hi);
        }
        const float4* s2 = (const float4*)w2;  float4* d2 = (float4*)w2s;
        for (int i = tid; i < W2N / 4; i += TPB) d2[i] = s2[i];
        const float2* sf1 = (const float2*)fw1;
        for (int i = tid; i < FW1H; i += TPB) { const float2 v = sf1[i]; fw1h[i] = pack2(v.x, v.y); }
        // fc2: fw2h[row][ch(4) @ 20 dw][m(20)]; m<15 = pack2(fw2[row][ch*30+2m], [+1])
        for (int i = tid; i < FW2P; i += TPB) {
            const int row = i / 80, c = i % 80, ch = c / 20, m = c % 20;
            unsigned int v = 0u;
            if (m < 15) v = pack2(fw2[row * 120 + ch * 30 + 2 * m],
                                  fw2[row * 120 + ch * 30 + 2 * m + 1]);
            fw2h[i] = v;
        }
        for (int i = tid; i < BIASN; i += TPB) {
            float v;
            if      (i < OB2)  v = b1[i];
            else if (i < OFB1) v = b2[i - OB2];
            else if (i < OFB2) v = fb1[i - OFB1];
            else if (i < OFW3) v = fb2[i - OFB2];
            else if (i < OFB3) v = fw3[i - OFW3];
            else               v = fb3[0];
            bias[i] = v;
        }
    }
    __syncthreads();

    const int lane4  = tid & 3;       // lane within sample quad
    const int lsamp  = tid >> 2;      // sample within block
    const int sample = blockIdx.x * SPB + lsamp;
    if (sample >= n) return;

    const int s  = state[sample];
    const int d  = des[sample];
    const int ai = act[sample];

    const int* asp = asp_g + s * 9;
    const int* pmp = pmp_g + s * 9;
    unsigned int* fslot = feat + lsamp * SLOT_DW;

    // ---- Cooperative gather: lane k handles positions k, k+4, k+8.
    // NEW_INDEX packed as nibbles: p -> {7,0,1,6,8,2,5,4,3}
#pragma unroll
    for (int t = 0; t < 3; ++t) {
        const int p = lane4 + 4 * t;
        if (p < 9) {
            const int a  = (int)((0x345286107ULL >> (4 * p)) & 0xF);
            const int na = asp[a];
            const float m = (float)pmp[a];
            const float4* pf = (const float4*)(path_feature + (na * DDIM + d) * PFN);
            const float4 v0 = pf[0], v1 = pf[1], v2 = pf[2];
            const float4* lf = (const float4*)(link_feature + na * LFN);
            const float4 u0 = lf[0], u1 = lf[1];
            unsigned int* dst = fslot + p * 11;   // 22 bf16 per position (dword aligned)
            dst[0] = pack2(v0.x, v0.y); dst[1] = pack2(v0.z, v0.w);
            dst[2] = pack2(v1.x, v1.y); dst[3] = pack2(v1.z, v1.w);
            dst[4] = pack2(v2.x, v2.y); dst[5] = pack2(v2.z, v2.w);
            dst[6] = pack2(u0.x, u0.y); dst[7] = pack2(u0.z, u0.w);
            dst[8] = pack2(u1.x, u1.y); dst[9] = pack2(u1.z, u1.w);
            dst[10] = pack2(m, 0.0f);             // channel 20 = mask, high half = pad
        }
    }
    // Quad writes its own slot; quads never cross a wave boundary, so
    // draining our wave's ds_writes orders the cross-lane reads.
    asm volatile("s_waitcnt lgkmcnt(0)" ::: "memory");

    // ---- conv1: lane k computes output channels [5k, 5k+5) via dot2 over
    // ic-pairs; 11 packed dwords cover all 21 channels (incl. mask, hi=0).
    const int oc0 = lane4 * 5;
    float o[5][9];
#pragma unroll
    for (int c = 0; c < 5; ++c) {
        const float bb = bias[OB1 + oc0 + c];
#pragma unroll
        for (int q = 0; q < 9; ++q) o[c][q] = bb;
    }

#pragma unroll 1
    for (int icp = 0; icp < 11; ++icp) {
        unsigned int fwd[9];
#pragma unroll
        for (int q = 0; q < 9; ++q) fwd[q] = fslot[q * 11 + icp];
        unsigned int wt[9];
#pragma unroll
        for (int c = 0; c < 5; ++c) {
            const unsigned int* wrow = w1p + (oc0 + c) * 99 + icp * 9;
#pragma unroll
            for (int t = 0; t < 9; ++t) wt[t] = wrow[t];
            conv_acc2(o[c], wt, fwd);
        }
    }

    // ---- lrelu + 2x2 maxpool (stride 1) on local 5 channels
    float pooled[5][4];
#pragma unroll
    for (int c = 0; c < 5; ++c) {
        float v[9];
#pragma unroll
        for (int q = 0; q < 9; ++q) v[q] = lrelu(o[c][q]);
        pooled[c][0] = fmaxf(fmaxf(v[0], v[1]), fmaxf(v[3], v[4]));
        pooled[c][1] = fmaxf(fmaxf(v[1], v[2]), fmaxf(v[4], v[5]));
        pooled[c][2] = fmaxf(fmaxf(v[3], v[4]), fmaxf(v[6], v[7]));
        pooled[c][3] = fmaxf(fmaxf(v[4], v[5]), fmaxf(v[7], v[8]));
    }

    // ---- conv2 (2x2 VALID): per-lane partial over its 5 oc (f32 weights from
    // LDS; quad starts {0,20,8,28} banks -> conflict-free), butterfly reduce.
    float x30[30];
#pragma unroll
    for (int j = 0; j < 30; ++j) {
        const float4* wr = (const float4*)(w2s + j * 80 + oc0 * 4);  // 16B aligned
        float acc = 0.0f;
#pragma unroll
        for (int c = 0; c < 5; ++c) {
            const float4 wv = wr[c];
            acc = fmaf(wv.x, pooled[c][0], acc);
            acc = fmaf(wv.y, pooled[c][1], acc);
            acc = fmaf(wv.z, pooled[c][2], acc);
            acc = fmaf(wv.w, pooled[c][3], acc);
        }
        acc += __shfl_xor(acc, 1, 64);
        acc += __shfl_xor(acc, 2, 64);
        x30[j] = lrelu(acc + bias[OB2 + j]);
    }

    // Pack x30 once to bf16 pairs for the dot2 FC path.
    unsigned int xp[15];
#pragma unroll
    for (int m = 0; m < 15; ++m) xp[m] = pack2(x30[2 * m], x30[2 * m + 1]);

    // ---- fc1 (38->120): lane k computes rows [30k, 30k+30) via dot2.
    float h1[30];
    const int j0 = lane4 * 30;
    const int ohd   = (30 + ai) >> 1;  // one-hot dword within 19-dw row
    const int ohodd = (30 + ai) & 1;   // which bf16 half
#pragma unroll
    for (int jj = 0; jj < 30; ++jj) {
        const unsigned int* wr = fw1h + (j0 + jj) * 19;
        const unsigned int uoh = wr[ohd];
        float acc = bias[OFB1 + j0 + jj] + (ohodd ? bfhi(uoh) : bflo(uoh));
#pragma unroll
        for (int m = 0; m < 15; ++m)
            acc = dot2bf(wr[m], xp[m], acc);
        h1[jj] = lrelu(acc);
    }

    // Pack h1 once to bf16 pairs.
    unsigned int hp[15];
#pragma unroll
    for (int m = 0; m < 15; ++m) hp[m] = pack2(h1[2 * m], h1[2 * m + 1]);

    // ---- fc2 (120->84) + fc3 (84->1): 4x conflict-free ds_read_b128 per
    // output (20-dw staggered chunks), DUAL-chain dot2 partial (8+7 split,
    // halved dependent latency), butterfly reduce, fold straight into fc3.
    float z = bias[OFB3];
#pragma unroll 2
    for (int i = 0; i < 84; ++i) {
        const uint4* w4 = (const uint4*)(fw2h + i * 80 + lane4 * 20);  // 80B-aligned
        const uint4 a0 = w4[0], a1 = w4[1], a2 = w4[2], a3 = w4[3];
        float alo = 0.0f, ahi = 0.0f;
        alo = dot2bf(a0.x, hp[0],  alo);  ahi = dot2bf(a2.x, hp[8],  ahi);
        alo = dot2bf(a0.y, hp[1],  alo);  ahi = dot2bf(a2.y, hp[9],  ahi);
        alo = dot2bf(a0.z, hp[2],  alo);  ahi = dot2bf(a2.z, hp[10], ahi);
        alo = dot2bf(a0.w, hp[3],  alo);  ahi = dot2bf(a2.w, hp[11], ahi);
        alo = dot2bf(a1.x, hp[4],  alo);  ahi = dot2bf(a3.x, hp[12], ahi);
        alo = dot2bf(a1.y, hp[5],  alo);  ahi = dot2bf(a3.y, hp[13], ahi);
        alo = dot2bf(a1.z, hp[6],  alo);  ahi = dot2bf(a3.z, hp[14], ahi);
        alo = dot2bf(a1.w, hp[7],  alo);
        float a = alo + ahi;
        a += __shfl_xor(a, 1, 64);
        a += __shfl_xor(a, 2, 64);
        z = fmaf(bias[OFW3 + i], lrelu(a + bias[OFB2 + i]), z);
    }

    if (lane4 == 0)
        out[sample] = 1.0f / (1.0f + __expf(-z));
}

extern "C" void kernel_launch(void* const* d_in, const int* in_sizes, int n_in,
                              void* d_out, int out_size, void* d_ws, size_t ws_size,
                              hipStream_t stream) {
    const int*   state = (const int*)d_in[0];
    const int*   des   = (const int*)d_in[1];
    const int*   act   = (const int*)d_in[2];
    const int*   asp   = (const int*)d_in[3];
    const int*   pmp   = (const int*)d_in[4];
    const float* pathf = (const float*)d_in[5];
    const float* linkf = (const float*)d_in[6];
    const float* w1    = (const float*)d_in[7];
    const float* b1    = (const float*)d_in[8];
    const float* w2    = (const float*)d_in[9];
    const float* b2    = (const float*)d_in[10];
    const float* fw1   = (const float*)d_in[11];
    const float* fb1   = (const float*)d_in[12];
    const float* fw2   = (const float*)d_in[13];
    const float* fb2   = (const float*)d_in[14];
    const float* fw3   = (const float*)d_in[15];
    const float* fb3   = (const float*)d_in[16];

    const int n = in_sizes[0];
    dim3 grid((n + SPB - 1) / SPB), block(TPB);
    hipLaunchKernelGGL(disc_kernel, grid, block, 0, stream,
                       state, des, act, asp, pmp, pathf, linkf,
                       w1, b1, w2, b2, fw1, fb1, fw2, fb2, fw3, fb3,
                       (float*)d_out, n);
}